// Round 2
// baseline (417.537 us; speedup 1.0000x reference)
//
#include <hip/hip_runtime.h>
#include <hip/hip_bf16.h>

typedef __attribute__((ext_vector_type(8))) short short8;   // 8 bf16 (4 VGPRs)
typedef __attribute__((ext_vector_type(4))) float f32x4;    // MFMA acc

#define NH   4
#define NB   1024
#define NL   200
#define NDQ  512
#define NDF  128
#define ND1  128
#define ND2  64
#define LPAD 208            // 13 * 16
#define KP   136            // padded k-stride (bf16 elems) -> 272B rows (16B-aligned)

// workspace layout (bytes)
#define OFF_WQC   0                                    // fp32 [H][512][64]   524288
#define OFF_BQC   (NH*NDQ*ND2*4)                       // fp32 [H][64]
#define OFF_FQ    (OFF_BQC + NH*ND2*4)                 // fp32 [H][B][64]     1048576
#define OFF_WIMG  (OFF_FQ + NH*NB*ND2*4)               // bf16 [H][3][64][KP] (slots: Wf_hi, Wf_lo, Wv_hi)
#define OFF_BFC   (OFF_WIMG + NH*3*ND2*KP*2)           // fp32 [H][64]
#define OFF_BVC   (OFF_BFC + NH*ND2*4)                 // fp32 [H][64]
// total ~1.78 MB

__device__ inline short f2bf(float f) {                // RN-even fp32 -> bf16 bits
    union { float f; unsigned u; } v; v.f = f;
    unsigned r = (v.u + 0x7FFFu + ((v.u >> 16) & 1u)) >> 16;
    return (short)r;
}
__device__ inline float bf2f(short s) {
    union { unsigned u; float f; } v; v.u = ((unsigned)(unsigned short)s) << 16;
    return v.f;
}

// ---------------- K1: fuse weights (identity between FC layers) ----------------
__global__ __launch_bounds__(256) void k_combine(
    const float* __restrict__ Wq1, const float* __restrict__ bq1,
    const float* __restrict__ Wq2, const float* __restrict__ bq2,
    const float* __restrict__ Wf1, const float* __restrict__ bf1,
    const float* __restrict__ Wf2, const float* __restrict__ bf2,
    const float* __restrict__ Wv1, const float* __restrict__ bv1,
    const float* __restrict__ Wv2, const float* __restrict__ bv2,
    float* __restrict__ WQC, float* __restrict__ BQC,
    __hip_bfloat16* __restrict__ WIMG, float* __restrict__ BFC, float* __restrict__ BVC)
{
    int g = blockIdx.x * 256 + threadIdx.x;
    if (g < NH*NDQ*ND2) {                       // Wqc = Wq1@Wq2 (fp32 exact)
        int h = g >> 15, r = g & 32767, i = r >> 6, j = r & 63;
        const float* a  = Wq1 + (h*NDQ + i)*ND1;
        const float* bb = Wq2 + h*ND1*ND2 + j;
        float s = 0.f;
        for (int k = 0; k < ND1; ++k) s += a[k] * bb[k*ND2];
        WQC[(h*NDQ + i)*ND2 + j] = s;
        return;
    }
    g -= NH*NDQ*ND2;
    if (g < 2*NH*NDF*ND2) {                     // Wfc (hi+lo) / Wvc (hi), transposed+padded image
        int which = (g >= NH*NDF*ND2);
        int r0 = g & (NH*NDF*ND2 - 1);
        int h = r0 >> 13, r = r0 & 8191, i = r >> 6, j = r & 63;
        const float* W1 = (which ? Wv1 : Wf1) + (h*NDF + i)*ND1;
        const float* W2 = (which ? Wv2 : Wf2) + h*ND1*ND2 + j;
        float s = 0.f;
        for (int k = 0; k < ND1; ++k) s += W1[k] * W2[k*ND2];
        short hi = f2bf(s);
        short lo = f2bf(s - bf2f(hi));
        __hip_bfloat16* img = WIMG + (size_t)((h*3 + (which ? 2 : 0))*ND2 + j)*KP + i; // [col=j][k=i]
        ((short*)img)[0] = hi;
        if (!which) ((short*)img)[ND2*KP] = lo;  // Wf lo slot
        return;
    }
    g -= 2*NH*NDF*ND2;
    if (g < NH*ND2) {                           // bqc = bq1@Wq2 + bq2
        int h = g >> 6, j = g & 63;
        float s = bq2[h*ND2 + j];
        for (int k = 0; k < ND1; ++k) s += bq1[h*ND1 + k] * Wq2[(h*ND1 + k)*ND2 + j];
        BQC[g] = s; return;
    }
    g -= NH*ND2;
    if (g < NH*ND2) {
        int h = g >> 6, j = g & 63;
        float s = bf2[h*ND2 + j];
        for (int k = 0; k < ND1; ++k) s += bf1[h*ND1 + k] * Wf2[(h*ND1 + k)*ND2 + j];
        BFC[g] = s; return;
    }
    g -= NH*ND2;
    if (g < NH*ND2) {
        int h = g >> 6, j = g & 63;
        float s = bv2[h*ND2 + j];
        for (int k = 0; k < ND1; ++k) s += bv1[h*ND1 + k] * Wv2[(h*ND1 + k)*ND2 + j];
        BVC[g] = s; return;
    }
}

// ---------------- K2: fq = silu(q @ Wqc + bqc), exact fp32 ----------------
// block = 8 batches; t -> (h = t>>6, d = t&63); grid = B/8 = 128
__global__ __launch_bounds__(256) void k_fq(
    const float* __restrict__ query, const float* __restrict__ WQC,
    const float* __restrict__ BQC, float* __restrict__ FQ)
{
    __shared__ __align__(16) float qS[8*NDQ];
    const int t = threadIdx.x;
    const int b0 = blockIdx.x * 8;
    {
        const float4* src = (const float4*)(query + (size_t)b0 * NDQ);
        float4* dst = (float4*)qS;
        for (int i = t; i < 8*NDQ/4; i += 256) dst[i] = src[i];
    }
    __syncthreads();
    const int h = t >> 6, d = t & 63;
    float s[8];
    {
        float b = BQC[h*ND2 + d];
        for (int g = 0; g < 8; ++g) s[g] = b;
    }
    const float* wp = WQC + (size_t)h*NDQ*ND2 + d;
    for (int i = 0; i < NDQ; ++i) {
        float w = wp[i*ND2];
        for (int g = 0; g < 8; ++g) s[g] += qS[g*NDQ + i] * w;
    }
    for (int g = 0; g < 8; ++g) {
        float v = s[g];
        FQ[((size_t)h*NB + b0 + g)*ND2 + d] = v / (1.f + expf(-v));
    }
}

// ---------------- K3: main fused attention ----------------
// 512 threads (8 warps). Warp w owns M-tiles {w, w+8} (13 tiles total).
__global__ __launch_bounds__(512, 2) void k_main(
    const float* __restrict__ fact,
    const int* __restrict__ mask,
    const float* __restrict__ mmc,
    const float* __restrict__ tau1,
    const float* __restrict__ tau2,
    const float* __restrict__ FQ,
    const float* __restrict__ BFC,
    const float* __restrict__ BVC,
    const __hip_bfloat16* __restrict__ WIMG,
    float* __restrict__ out)
{
    __shared__ __align__(16) __hip_bfloat16 wS[2*ND2*KP];   // 34816 B
    __shared__ __align__(16) float dotS[LPAD];
    __shared__ __align__(16) float alphaS[LPAD];
    __shared__ __align__(16) float redS[8];
    __shared__ __align__(16) float outPartS[512];

    const int t    = threadIdx.x;
    const int b    = blockIdx.x;
    const int w    = t >> 6;
    const int lane = t & 63;
    const int a15  = lane & 15;
    const int quad = lane >> 4;
    const int nmt  = (w < 5) ? 2 : 1;           // 13 M-tiles over 8 warps

    // A fragments: fact[b] split hi/lo bf16, resident in registers.
    // A-layout (16x16x32): lane holds A[m=lane&15][k=quad*8+j]
    short8 afh[2][4], afl[2][4];
    const short8 zero8 = {0,0,0,0,0,0,0,0};
    for (int mi = 0; mi < 2; ++mi) {
        int mt = w + 8*mi;
        int row = mt*16 + a15;
        for (int kk = 0; kk < 4; ++kk) {
            short8 vh = zero8, vl = zero8;
            if (mt < 13 && row < NL) {
                const float* p = fact + ((size_t)(b*NL + row))*NDF + kk*32 + quad*8;
                float4 x0 = *(const float4*)p;
                float4 x1 = *(const float4*)(p + 4);
                float v[8] = {x0.x, x0.y, x0.z, x0.w, x1.x, x1.y, x1.z, x1.w};
                for (int j = 0; j < 8; ++j) {
                    short hs = f2bf(v[j]);
                    vh[j] = hs;
                    vl[j] = f2bf(v[j] - bf2f(hs));
                }
            }
            afh[mi][kk] = vh;
            afl[mi][kk] = vl;
        }
    }

    const int bL = b * NL;
    const f32x4 zf = {0.f, 0.f, 0.f, 0.f};

    for (int h = 0; h < NH; ++h) {
        __syncthreads();                        // prev head done with wS/outPartS
        {   // stage Wf hi+lo (2176 float4)
            const float4* src = (const float4*)(WIMG + (size_t)(h*3)*ND2*KP);
            float4* dst = (float4*)wS;
            for (int i = t; i < 2176; i += 512) dst[i] = src[i];
        }
        float fqv[4], bfcv[4], bvcv[4];
        for (int nt = 0; nt < 4; ++nt) {
            int col = nt*16 + a15;
            fqv[nt]  = FQ[((size_t)h*NB + b)*ND2 + col];
            bfcv[nt] = BFC[h*ND2 + col];
            bvcv[nt] = BVC[h*ND2 + col];
        }
        const float t1a = tau1[h];
        const float t1b = tau1[NH + h];
        const float t20 = tau2[h];
        const float t21 = tau2[NH + h];
        const float t22 = tau2[2*NH + h];
        __syncthreads();                        // wS ready

        // ---- ff GEMM, 3 passes: f_hi*w_hi + f_hi*w_lo + f_lo*w_hi ----
        f32x4 acc[2][4];
        for (int mi = 0; mi < 2; ++mi) for (int nt = 0; nt < 4; ++nt) acc[mi][nt] = zf;
        for (int kk = 0; kk < 4; ++kk) {
            short8 bh[4], bl[4];
            for (int nt = 0; nt < 4; ++nt) {
                const __hip_bfloat16* p = wS + (nt*16 + a15)*KP + kk*32 + quad*8;
                bh[nt] = *(const short8*)p;
                bl[nt] = *(const short8*)(p + ND2*KP);
            }
            for (int mi = 0; mi < 2; ++mi)
                if (mi < nmt)
                    for (int nt = 0; nt < 4; ++nt) {
                        acc[mi][nt] = __builtin_amdgcn_mfma_f32_16x16x32_bf16(afh[mi][kk], bh[nt], acc[mi][nt], 0, 0, 0);
                        acc[mi][nt] = __builtin_amdgcn_mfma_f32_16x16x32_bf16(afh[mi][kk], bl[nt], acc[mi][nt], 0, 0, 0);
                        acc[mi][nt] = __builtin_amdgcn_mfma_f32_16x16x32_bf16(afl[mi][kk], bh[nt], acc[mi][nt], 0, 0, 0);
                    }
        }

        // ---- epilogue: silu, dot with fq, reduce 16 cols held across lanes ----
        for (int mi = 0; mi < 2; ++mi)
            if (mi < nmt) {
                int mt = w + 8*mi;
                for (int rg = 0; rg < 4; ++rg) {
                    float s = 0.f;
                    for (int nt = 0; nt < 4; ++nt) {
                        float z = acc[mi][nt][rg] + bfcv[nt];
                        float ffv = z / (1.f + expf(-z));
                        s += ffv * fqv[nt];
                    }
                    s += __shfl_xor(s, 1);
                    s += __shfl_xor(s, 2);
                    s += __shfl_xor(s, 4);
                    s += __shfl_xor(s, 8);
                    if (a15 == rg) dotS[mt*16 + quad*4 + rg] = s;
                }
            }
        __syncthreads();

        {   // stage Wv_hi (1088 float4) — consumed after the softmax barriers
            const float4* src = (const float4*)(WIMG + (size_t)(h*3 + 2)*ND2*KP);
            float4* dst = (float4*)wS;
            for (int i = t; i < 1088; i += 512) dst[i] = src[i];
        }

        // ---- logits exactly per reference, softmax over L ----
        float logit = -3.0e38f;
        float e = 0.f;
        if (t < NL) {
            float dv = dotS[t] - 1e9f * (1.0f - (float)mask[bL + t]);
            float bias = mmc[bL + t] / t1a + mmc[NB*NL + bL + t] / t1b;
            logit = t20*dv + t21*bias + t22*dv*bias;
        }
        float vmax = logit;
        for (int off = 1; off < 64; off <<= 1) vmax = fmaxf(vmax, __shfl_xor(vmax, off));
        if (lane == 0) redS[w] = vmax;
        __syncthreads();
        vmax = redS[0];
        for (int i = 1; i < 8; ++i) vmax = fmaxf(vmax, redS[i]);
        if (t < NL) e = expf(logit - vmax);
        float vsum = e;
        for (int off = 1; off < 64; off <<= 1) vsum += __shfl_xor(vsum, off);
        __syncthreads();
        if (lane == 0) redS[w] = vsum;
        __syncthreads();
        vsum = 0.f;
        for (int i = 0; i < 8; ++i) vsum += redS[i];
        if (t < LPAD) alphaS[t] = (t < NL) ? (e / vsum + 1e-7f) : 0.f;
        __syncthreads();

        // ---- fv GEMM: single hi*hi pass (2% tolerance on outputs) ----
        for (int mi = 0; mi < 2; ++mi) for (int nt = 0; nt < 4; ++nt) acc[mi][nt] = zf;
        for (int kk = 0; kk < 4; ++kk) {
            short8 bh[4];
            for (int nt = 0; nt < 4; ++nt)
                bh[nt] = *(const short8*)(wS + (nt*16 + a15)*KP + kk*32 + quad*8);
            for (int mi = 0; mi < 2; ++mi)
                if (mi < nmt)
                    for (int nt = 0; nt < 4; ++nt)
                        acc[mi][nt] = __builtin_amdgcn_mfma_f32_16x16x32_bf16(afh[mi][kk], bh[nt], acc[mi][nt], 0, 0, 0);
        }

        // ---- AV: out[col] = sum_l alpha[l] * silu(fv[l][col]) ----
        float o[4] = {0.f, 0.f, 0.f, 0.f};
        for (int mi = 0; mi < 2; ++mi)
            if (mi < nmt) {
                int mt = w + 8*mi;
                const f32x4 al = *(const f32x4*)(alphaS + mt*16 + quad*4);
                for (int rg = 0; rg < 4; ++rg)
                    for (int nt = 0; nt < 4; ++nt) {
                        float z = acc[mi][nt][rg] + bvcv[nt];
                        float fvv = z / (1.f + expf(-z));
                        o[nt] += al[rg] * fvv;
                    }
            }
        for (int nt = 0; nt < 4; ++nt) {
            o[nt] += __shfl_xor(o[nt], 16);
            o[nt] += __shfl_xor(o[nt], 32);
        }
        if (lane < 16)
            for (int nt = 0; nt < 4; ++nt) outPartS[w*64 + nt*16 + lane] = o[nt];
        __syncthreads();
        if (t < 64) {
            float s = 0.f;
            for (int ww = 0; ww < 8; ++ww) s += outPartS[ww*64 + t];
            out[(size_t)b*(NH*ND2) + h*ND2 + t] = s;
        }
    }
}

extern "C" void kernel_launch(void* const* d_in, const int* in_sizes, int n_in,
                              void* d_out, int out_size, void* d_ws, size_t ws_size,
                              hipStream_t stream) {
    const float* query = (const float*)d_in[0];
    const float* fact  = (const float*)d_in[1];
    const int*   maskp = (const int*)d_in[2];
    const float* mmc   = (const float*)d_in[3];
    const float* Wq1 = (const float*)d_in[4];
    const float* bq1 = (const float*)d_in[5];
    const float* Wq2 = (const float*)d_in[6];
    const float* bq2 = (const float*)d_in[7];
    const float* Wf1 = (const float*)d_in[8];
    const float* bf1 = (const float*)d_in[9];
    const float* Wf2 = (const float*)d_in[10];
    const float* bf2 = (const float*)d_in[11];
    const float* Wv1 = (const float*)d_in[12];
    const float* bv1 = (const float*)d_in[13];
    const float* Wv2 = (const float*)d_in[14];
    const float* bv2 = (const float*)d_in[15];
    const float* tau1 = (const float*)d_in[16];
    const float* tau2 = (const float*)d_in[17];

    char* ws = (char*)d_ws;
    float*          WQC  = (float*)(ws + OFF_WQC);
    float*          BQC  = (float*)(ws + OFF_BQC);
    float*          FQ   = (float*)(ws + OFF_FQ);
    __hip_bfloat16* WIMG = (__hip_bfloat16*)(ws + OFF_WIMG);
    float*          BFC  = (float*)(ws + OFF_BFC);
    float*          BVC  = (float*)(ws + OFF_BVC);

    k_combine<<<771, 256, 0, stream>>>(Wq1, bq1, Wq2, bq2, Wf1, bf1, Wf2, bf2,
                                       Wv1, bv1, Wv2, bv2, WQC, BQC, WIMG, BFC, BVC);
    k_fq<<<NB/8, 256, 0, stream>>>(query, WQC, BQC, FQ);
    k_main<<<NB, 512, 0, stream>>>(fact, maskp, mmc, tau1, tau2, FQ, BFC, BVC, WIMG,
                                   (float*)d_out);
}

// Round 3
// 383.761 us; speedup vs baseline: 1.0880x; 1.0880x over previous
//
#include <hip/hip_runtime.h>
#include <hip/hip_bf16.h>

typedef __attribute__((ext_vector_type(8))) short short8;   // 8 bf16 (4 VGPRs)
typedef __attribute__((ext_vector_type(4))) float f32x4;    // MFMA acc

#define NH   4
#define NB   1024
#define NL   200
#define NDQ  512
#define NDF  128
#define ND1  128
#define ND2  64
#define LPAD 208            // 13 * 16
#define KP   136            // padded k-stride (bf16 elems) -> 272B rows (16B-aligned)

// workspace layout (bytes)
#define OFF_WQC   0                                    // fp32 [H][512][64]   524288
#define OFF_BQC   (NH*NDQ*ND2*4)                       // fp32 [H][64]
#define OFF_FQ    (OFF_BQC + NH*ND2*4)                 // fp32 [H][B][64]
#define OFF_WIMG  (OFF_FQ + NH*NB*ND2*4)               // bf16 [H][3][64][KP] (slots: Wf_hi, Wf_lo, Wv_hi)
#define OFF_BFC   (OFF_WIMG + NH*3*ND2*KP*2)           // fp32 [H][64]
#define OFF_BVC   (OFF_BFC + NH*ND2*4)                 // fp32 [H][64]

__device__ inline short f2bf(float f) {                // RN-even fp32 -> bf16 bits
    union { float f; unsigned u; } v; v.f = f;
    unsigned r = (v.u + 0x7FFFu + ((v.u >> 16) & 1u)) >> 16;
    return (short)r;
}
__device__ inline float bf2f(short s) {
    union { unsigned u; float f; } v; v.u = ((unsigned)(unsigned short)s) << 16;
    return v.f;
}
__device__ inline float fsilu(float z) {               // fast silu: ~2 ulp, 5 VALU ops
    return z * __fdividef(1.f, 1.f + __expf(-z));
}

// ---------------- K1: fuse weights (identity between FC layers) ----------------
__global__ __launch_bounds__(256) void k_combine(
    const float* __restrict__ Wq1, const float* __restrict__ bq1,
    const float* __restrict__ Wq2, const float* __restrict__ bq2,
    const float* __restrict__ Wf1, const float* __restrict__ bf1,
    const float* __restrict__ Wf2, const float* __restrict__ bf2,
    const float* __restrict__ Wv1, const float* __restrict__ bv1,
    const float* __restrict__ Wv2, const float* __restrict__ bv2,
    float* __restrict__ WQC, float* __restrict__ BQC,
    __hip_bfloat16* __restrict__ WIMG, float* __restrict__ BFC, float* __restrict__ BVC)
{
    int g = blockIdx.x * 256 + threadIdx.x;
    if (g < NH*NDQ*ND2) {                       // Wqc = Wq1@Wq2 (fp32 exact)
        int h = g >> 15, r = g & 32767, i = r >> 6, j = r & 63;
        const float* a  = Wq1 + (h*NDQ + i)*ND1;
        const float* bb = Wq2 + h*ND1*ND2 + j;
        float s = 0.f;
        for (int k = 0; k < ND1; ++k) s += a[k] * bb[k*ND2];
        WQC[(h*NDQ + i)*ND2 + j] = s;
        return;
    }
    g -= NH*NDQ*ND2;
    if (g < 2*NH*NDF*ND2) {                     // Wfc (hi+lo) / Wvc (hi), transposed+padded image
        int which = (g >= NH*NDF*ND2);
        int r0 = g & (NH*NDF*ND2 - 1);
        int h = r0 >> 13, r = r0 & 8191, i = r >> 6, j = r & 63;
        const float* W1 = (which ? Wv1 : Wf1) + (h*NDF + i)*ND1;
        const float* W2 = (which ? Wv2 : Wf2) + h*ND1*ND2 + j;
        float s = 0.f;
        for (int k = 0; k < ND1; ++k) s += W1[k] * W2[k*ND2];
        short hi = f2bf(s);
        short lo = f2bf(s - bf2f(hi));
        __hip_bfloat16* img = WIMG + (size_t)((h*3 + (which ? 2 : 0))*ND2 + j)*KP + i; // [col=j][k=i]
        ((short*)img)[0] = hi;
        if (!which) ((short*)img)[ND2*KP] = lo;  // Wf lo slot
        return;
    }
    g -= 2*NH*NDF*ND2;
    if (g < NH*ND2) {                           // bqc = bq1@Wq2 + bq2
        int h = g >> 6, j = g & 63;
        float s = bq2[h*ND2 + j];
        for (int k = 0; k < ND1; ++k) s += bq1[h*ND1 + k] * Wq2[(h*ND1 + k)*ND2 + j];
        BQC[g] = s; return;
    }
    g -= NH*ND2;
    if (g < NH*ND2) {
        int h = g >> 6, j = g & 63;
        float s = bf2[h*ND2 + j];
        for (int k = 0; k < ND1; ++k) s += bf1[h*ND1 + k] * Wf2[(h*ND1 + k)*ND2 + j];
        BFC[g] = s; return;
    }
    g -= NH*ND2;
    if (g < NH*ND2) {
        int h = g >> 6, j = g & 63;
        float s = bv2[h*ND2 + j];
        for (int k = 0; k < ND1; ++k) s += bv1[h*ND1 + k] * Wv2[(h*ND1 + k)*ND2 + j];
        BVC[g] = s; return;
    }
}

// ---------------- K2: fq = silu(q @ Wqc + bqc) ----------------
// 256 blocks x 4 batches; t -> (h = t>>6, d = t&63)
__global__ __launch_bounds__(256) void k_fq(
    const float* __restrict__ query, const float* __restrict__ WQC,
    const float* __restrict__ BQC, float* __restrict__ FQ)
{
    __shared__ __align__(16) float qS[4*NDQ];
    const int t = threadIdx.x;
    const int b0 = blockIdx.x * 4;
    {
        const float4* src = (const float4*)(query + (size_t)b0 * NDQ);
        float4* dst = (float4*)qS;
        dst[t] = src[t];
        dst[t + 256] = src[t + 256];
    }
    __syncthreads();
    const int h = t >> 6, d = t & 63;
    float s0, s1, s2, s3;
    s0 = s1 = s2 = s3 = BQC[h*ND2 + d];
    const float* wp = WQC + (size_t)h*NDQ*ND2 + d;
    #pragma unroll 8
    for (int i = 0; i < NDQ; ++i) {
        float wv = wp[i*ND2];
        s0 += qS[i]        * wv;
        s1 += qS[NDQ + i]  * wv;
        s2 += qS[2*NDQ + i]* wv;
        s3 += qS[3*NDQ + i]* wv;
    }
    float* o = FQ + ((size_t)h*NB + b0)*ND2 + d;
    o[0]      = fsilu(s0);
    o[ND2]    = fsilu(s1);
    o[2*ND2]  = fsilu(s2);
    o[3*ND2]  = fsilu(s3);
}

// ---------------- K3: main fused attention ----------------
// 512 threads (8 warps). Warp w owns M-tiles {w, w+8} (13 tiles total).
// 3 barriers per head: [top] stage -> [B2] GEMM+dot -> [B3] warp-local softmax + fv + AV
__global__ __launch_bounds__(512, 2) void k_main(
    const float* __restrict__ fact,
    const int* __restrict__ mask,
    const float* __restrict__ mmc,
    const float* __restrict__ tau1,
    const float* __restrict__ tau2,
    const float* __restrict__ FQ,
    const float* __restrict__ BFC,
    const float* __restrict__ BVC,
    const __hip_bfloat16* __restrict__ WIMG,
    float* __restrict__ out)
{
    __shared__ __align__(16) __hip_bfloat16 wS[3*ND2*KP];   // 52224 B: Wf_hi, Wf_lo, Wv_hi
    __shared__ __align__(16) float dotS[LPAD];
    __shared__ __align__(16) float outPartS[512];

    const int t    = threadIdx.x;
    const int b    = blockIdx.x;
    const int w    = t >> 6;
    const int lane = t & 63;
    const int a15  = lane & 15;
    const int quad = lane >> 4;
    const int nmt  = (w < 5) ? 2 : 1;           // 13 M-tiles over 8 warps

    // A fragments: fact[b] split hi/lo bf16, resident in registers for all heads.
    // A-layout (16x16x32): lane holds A[m=lane&15][k=quad*8+j]
    short8 afh[2][4], afl[2][4];
    const short8 zero8 = {0,0,0,0,0,0,0,0};
    for (int mi = 0; mi < 2; ++mi) {
        int mt = w + 8*mi;
        int row = mt*16 + a15;
        for (int kk = 0; kk < 4; ++kk) {
            short8 vh = zero8, vl = zero8;
            if (mt < 13 && row < NL) {
                const float* p = fact + ((size_t)(b*NL + row))*NDF + kk*32 + quad*8;
                float4 x0 = *(const float4*)p;
                float4 x1 = *(const float4*)(p + 4);
                float v[8] = {x0.x, x0.y, x0.z, x0.w, x1.x, x1.y, x1.z, x1.w};
                for (int j = 0; j < 8; ++j) {
                    short hs = f2bf(v[j]);
                    vh[j] = hs;
                    vl[j] = f2bf(v[j] - bf2f(hs));
                }
            }
            afh[mi][kk] = vh;
            afl[mi][kk] = vl;
        }
    }

    const int bL = b * NL;
    const f32x4 zf = {0.f, 0.f, 0.f, 0.f};

    for (int h = 0; h < NH; ++h) {
        __syncthreads();                        // top: outPartS(h-1) complete; wS(h-1) reads done
        if (h > 0 && t < 64) {                  // drain previous head's output
            float s = 0.f;
            for (int ww = 0; ww < 8; ++ww) s += outPartS[ww*64 + t];
            out[(size_t)b*(NH*ND2) + (h-1)*ND2 + t] = s;
        }
        {   // stage Wf_hi + Wf_lo + Wv_hi (3264 float4)
            const float4* src = (const float4*)(WIMG + (size_t)(h*3)*ND2*KP);
            float4* dst = (float4*)wS;
            for (int i = t; i < 3264; i += 512) dst[i] = src[i];
        }
        float fqv[4], bfcv[4], bvcv[4];
        for (int nt = 0; nt < 4; ++nt) {
            int col = nt*16 + a15;
            fqv[nt]  = FQ[((size_t)h*NB + b)*ND2 + col];
            bfcv[nt] = BFC[h*ND2 + col];
            bvcv[nt] = BVC[h*ND2 + col];
        }
        const float t1a = tau1[h];
        const float t1b = tau1[NH + h];
        const float t20 = tau2[h];
        const float t21 = tau2[NH + h];
        const float t22 = tau2[2*NH + h];
        __syncthreads();                        // B2: wS ready

        // ---- ff GEMM, 3 passes: f_hi*w_hi + f_hi*w_lo + f_lo*w_hi ----
        f32x4 acc[2][4];
        for (int mi = 0; mi < 2; ++mi) for (int nt = 0; nt < 4; ++nt) acc[mi][nt] = zf;
        for (int kk = 0; kk < 4; ++kk) {
            short8 bh[4], bl[4];
            for (int nt = 0; nt < 4; ++nt) {
                const __hip_bfloat16* p = wS + (nt*16 + a15)*KP + kk*32 + quad*8;
                bh[nt] = *(const short8*)p;
                bl[nt] = *(const short8*)(p + ND2*KP);
            }
            for (int mi = 0; mi < 2; ++mi)
                if (mi < nmt)
                    for (int nt = 0; nt < 4; ++nt) {
                        acc[mi][nt] = __builtin_amdgcn_mfma_f32_16x16x32_bf16(afh[mi][kk], bh[nt], acc[mi][nt], 0, 0, 0);
                        acc[mi][nt] = __builtin_amdgcn_mfma_f32_16x16x32_bf16(afh[mi][kk], bl[nt], acc[mi][nt], 0, 0, 0);
                        acc[mi][nt] = __builtin_amdgcn_mfma_f32_16x16x32_bf16(afl[mi][kk], bh[nt], acc[mi][nt], 0, 0, 0);
                    }
        }

        // ---- epilogue: silu, dot with fq, reduce 16 cols held across lanes ----
        for (int mi = 0; mi < 2; ++mi)
            if (mi < nmt) {
                int mt = w + 8*mi;
                for (int rg = 0; rg < 4; ++rg) {
                    float s = 0.f;
                    for (int nt = 0; nt < 4; ++nt)
                        s += fsilu(acc[mi][nt][rg] + bfcv[nt]) * fqv[nt];
                    s += __shfl_xor(s, 1);
                    s += __shfl_xor(s, 2);
                    s += __shfl_xor(s, 4);
                    s += __shfl_xor(s, 8);
                    if (a15 == rg) dotS[mt*16 + quad*4 + rg] = s;
                }
            }
        __syncthreads();                        // B3: dotS ready

        // ---- warp-local softmax (no block barriers): each warp covers all 200 rows ----
        float lg[4];
        float vmax = -3.0e38f;
        #pragma unroll
        for (int j = 0; j < 4; ++j) {
            int r = lane + 64*j;
            float l = -3.0e38f;
            if (r < NL) {
                float dv = dotS[r] - 1e9f * (1.0f - (float)mask[bL + r]);
                float bias = __fdividef(mmc[bL + r], t1a) + __fdividef(mmc[NB*NL + bL + r], t1b);
                l = t20*dv + t21*bias + t22*dv*bias;
            }
            lg[j] = l;
            vmax = fmaxf(vmax, l);
        }
        #pragma unroll
        for (int off = 1; off < 64; off <<= 1) vmax = fmaxf(vmax, __shfl_xor(vmax, off));
        float vsum = 0.f;
        #pragma unroll
        for (int j = 0; j < 4; ++j)
            if (lane + 64*j < NL) vsum += __expf(lg[j] - vmax);
        #pragma unroll
        for (int off = 1; off < 64; off <<= 1) vsum += __shfl_xor(vsum, off);
        const float rdenom = __fdividef(1.f, vsum);

        // per-lane alphas for the rows this lane's accumulators cover
        float al[2][4];
        for (int mi = 0; mi < 2; ++mi)
            for (int rg = 0; rg < 4; ++rg) {
                float a = 0.f;
                if (mi < nmt) {
                    int r = (w + 8*mi)*16 + quad*4 + rg;
                    if (r < NL) {
                        float dv = dotS[r] - 1e9f * (1.0f - (float)mask[bL + r]);
                        float bias = __fdividef(mmc[bL + r], t1a) + __fdividef(mmc[NB*NL + bL + r], t1b);
                        float l = t20*dv + t21*bias + t22*dv*bias;
                        a = __expf(l - vmax) * rdenom + 1e-7f;
                    }
                }
                al[mi][rg] = a;
            }

        // ---- fv GEMM: single hi*hi pass (slot 2) ----
        for (int mi = 0; mi < 2; ++mi) for (int nt = 0; nt < 4; ++nt) acc[mi][nt] = zf;
        for (int kk = 0; kk < 4; ++kk) {
            short8 bh[4];
            for (int nt = 0; nt < 4; ++nt)
                bh[nt] = *(const short8*)(wS + (2*ND2 + nt*16 + a15)*KP + kk*32 + quad*8);
            for (int mi = 0; mi < 2; ++mi)
                if (mi < nmt)
                    for (int nt = 0; nt < 4; ++nt)
                        acc[mi][nt] = __builtin_amdgcn_mfma_f32_16x16x32_bf16(afh[mi][kk], bh[nt], acc[mi][nt], 0, 0, 0);
        }

        // ---- AV: out[col] = sum_l alpha[l] * silu(fv[l][col]) ----
        float o[4] = {0.f, 0.f, 0.f, 0.f};
        for (int mi = 0; mi < 2; ++mi)
            if (mi < nmt)
                for (int rg = 0; rg < 4; ++rg)
                    for (int nt = 0; nt < 4; ++nt)
                        o[nt] += al[mi][rg] * fsilu(acc[mi][nt][rg] + bvcv[nt]);
        for (int nt = 0; nt < 4; ++nt) {
            o[nt] += __shfl_xor(o[nt], 16);
            o[nt] += __shfl_xor(o[nt], 32);
        }
        if (lane < 16)
            for (int nt = 0; nt < 4; ++nt) outPartS[w*64 + nt*16 + lane] = o[nt];
    }
    __syncthreads();
    if (t < 64) {
        float s = 0.f;
        for (int ww = 0; ww < 8; ++ww) s += outPartS[ww*64 + t];
        out[(size_t)b*(NH*ND2) + (NH-1)*ND2 + t] = s;
    }
}

extern "C" void kernel_launch(void* const* d_in, const int* in_sizes, int n_in,
                              void* d_out, int out_size, void* d_ws, size_t ws_size,
                              hipStream_t stream) {
    const float* query = (const float*)d_in[0];
    const float* fact  = (const float*)d_in[1];
    const int*   maskp = (const int*)d_in[2];
    const float* mmc   = (const float*)d_in[3];
    const float* Wq1 = (const float*)d_in[4];
    const float* bq1 = (const float*)d_in[5];
    const float* Wq2 = (const float*)d_in[6];
    const float* bq2 = (const float*)d_in[7];
    const float* Wf1 = (const float*)d_in[8];
    const float* bf1 = (const float*)d_in[9];
    const float* Wf2 = (const float*)d_in[10];
    const float* bf2 = (const float*)d_in[11];
    const float* Wv1 = (const float*)d_in[12];
    const float* bv1 = (const float*)d_in[13];
    const float* Wv2 = (const float*)d_in[14];
    const float* bv2 = (const float*)d_in[15];
    const float* tau1 = (const float*)d_in[16];
    const float* tau2 = (const float*)d_in[17];

    char* ws = (char*)d_ws;
    float*          WQC  = (float*)(ws + OFF_WQC);
    float*          BQC  = (float*)(ws + OFF_BQC);
    float*          FQ   = (float*)(ws + OFF_FQ);
    __hip_bfloat16* WIMG = (__hip_bfloat16*)(ws + OFF_WIMG);
    float*          BFC  = (float*)(ws + OFF_BFC);
    float*          BVC  = (float*)(ws + OFF_BVC);

    k_combine<<<771, 256, 0, stream>>>(Wq1, bq1, Wq2, bq2, Wf1, bf1, Wf2, bf2,
                                       Wv1, bv1, Wv2, bv2, WQC, BQC, WIMG, BFC, BVC);
    k_fq<<<NB/4, 256, 0, stream>>>(query, WQC, BQC, FQ);
    k_main<<<NB, 512, 0, stream>>>(fact, maskp, mmc, tau1, tau2, FQ, BFC, BVC, WIMG,
                                   (float*)d_out);
}